// Round 7
// baseline (130.516 us; speedup 1.0000x reference)
//
#include <hip/hip_runtime.h>

// ChamferDistance2D: B=8, N=M=8192, fp32, scalar output.
// cost = sum_b [ mean_i min_j d(i,j) + mean_j min_i d(i,j) ],  d = squared L2.
// Store min_j of (|q_j|^2 - 2 p_i . q_j); add |p_i|^2 back in reduce.
//
// R15: structure round. Established across R8/R9/R10/R12/R14: partial is AT
// the fp32 vector-FMA issue roofline (~82k VALU-cyc/SIMD in EVERY variant:
// v_pk_fma_f32 is 4-cyc on SIMD-32 => FLOP-double, NOT issue-double; inst
// count, LDS traffic, occupancy all null levers). One-pass symmetric tiling
// audited: zero savings (z-terms fold free in fma addend slots). Partial
// stays = R10's proven 61.6us loop (IPT=8, unroll-8, SoA LDS, pk), S=16.
// The actionable gap: ~46us of per-iteration time in NO kernel, constant
// across 2/3/4-node graphs => fixed harness/reset cost + our tail. This
// round: (1) reduce+final fused via last-block pattern (release fence +
// acq_rel atomic counter; PLAIN kernels -- R13's coop failure was likely
// coop-launch-under-graph-capture, not math); (2) ws 16->8 MB (S=16).
// Decisive: total 110-116 => fixed-overhead confirmed, partial is the only
// lever left; <105 => node gaps were real; absmax fail => cross-XCD fence
// broken here, revert to 3 kernels.

#define BATCH 8
#define NPTS  8192
#define TPB   256
#define IPT   8
#define PPB   (TPB * IPT)            // 2048
#define TILES (NPTS / PPB)           // 4
#define S     16                     // j-splits
#define JCH   (NPTS / S)             // 512 j's per block
#define PARTN (2 * BATCH * S * NPTS) // floats in partial buffer (8 MB)
#define RBLKS (2 * BATCH * NPTS / TPB) // 512 reduce blocks

__device__ inline float min3f(float a, float b, float c) {
    float d;
    asm("v_min3_f32 %0, %1, %2, %3" : "=v"(d) : "v"(a), "v"(b), "v"(c));
    return d;
}

__device__ inline float2 pkfma(float2 a, float2 b, float2 c) {
    float2 d;
    asm("v_pk_fma_f32 %0, %1, %2, %3" : "=v"(d) : "v"(a), "v"(b), "v"(c));
    return d;
}

// grid.x = 2 * BATCH * TILES * S = 1024  (4 blocks/CU)
__global__ __launch_bounds__(TPB, 4)
void chamfer_partial(const float* __restrict__ p1, const float* __restrict__ p2,
                     float* __restrict__ partial /* [2][B][S][N] */,
                     int* __restrict__ counter) {
    __shared__ __align__(16) float qx[JCH];
    __shared__ __align__(16) float qy[JCH];
    __shared__ __align__(16) float qz[JCH];

    // reset the last-block counter for this iteration (ws is poisoned
    // between iterations; kernel-boundary ordering makes this visible
    // to chamfer_reduce_final).
    if (blockIdx.x == 0 && threadIdx.x == 0) *counter = 0;

    int blk   = blockIdx.x;
    int split = blk & (S - 1);      blk >>= 4;
    int tile  = blk & (TILES - 1);  blk >>= 2;
    int b     = blk & (BATCH - 1);  blk >>= 3;
    int dir   = blk;

    const float2* a  = (const float2*)(dir ? p2 : p1) + (size_t)b * NPTS;
    const float2* bp = (const float2*)(dir ? p1 : p2) + (size_t)b * NPTS + split * JCH;

    int t = threadIdx.x;

    for (int j = t; j < JCH; j += TPB) {
        float2 v = bp[j];
        qx[j] = v.x;
        qy[j] = v.y;
        qz[j] = fmaf(v.x, v.x, v.y * v.y);
    }

    int pt_base = tile * PPB;
    float2 xp2[IPT], yp2[IPT];
    float  m[IPT];
#pragma unroll
    for (int k = 0; k < IPT; ++k) {
        float2 v = a[pt_base + k * TPB + t];
        xp2[k] = make_float2(-2.0f * v.x, -2.0f * v.x);
        yp2[k] = make_float2(-2.0f * v.y, -2.0f * v.y);
        m[k]   = 3.0e38f;
    }

    __syncthreads();

    for (int j = 0; j < JCH; j += 8) {
        float4 x03 = *(const float4*)&qx[j];
        float4 x47 = *(const float4*)&qx[j + 4];
        float4 y03 = *(const float4*)&qy[j];
        float4 y47 = *(const float4*)&qy[j + 4];
        float4 z03 = *(const float4*)&qz[j];
        float4 z47 = *(const float4*)&qz[j + 4];
        float2 x01 = make_float2(x03.x, x03.y), x23 = make_float2(x03.z, x03.w);
        float2 x45 = make_float2(x47.x, x47.y), x67 = make_float2(x47.z, x47.w);
        float2 y01 = make_float2(y03.x, y03.y), y23 = make_float2(y03.z, y03.w);
        float2 y45 = make_float2(y47.x, y47.y), y67 = make_float2(y47.z, y47.w);
        float2 z01 = make_float2(z03.x, z03.y), z23 = make_float2(z03.z, z03.w);
        float2 z45 = make_float2(z47.x, z47.y), z67 = make_float2(z47.z, z47.w);
#pragma unroll
        for (int k = 0; k < IPT; ++k) {
            float2 a01 = pkfma(yp2[k], y01, pkfma(xp2[k], x01, z01));
            float2 a23 = pkfma(yp2[k], y23, pkfma(xp2[k], x23, z23));
            float2 a45 = pkfma(yp2[k], y45, pkfma(xp2[k], x45, z45));
            float2 a67 = pkfma(yp2[k], y67, pkfma(xp2[k], x67, z67));
            m[k] = min3f(m[k], a01.x, a01.y);
            m[k] = min3f(m[k], a23.x, a23.y);
            m[k] = min3f(m[k], a45.x, a45.y);
            m[k] = min3f(m[k], a67.x, a67.y);
        }
    }

    float* outp = partial + ((size_t)((dir * BATCH + b) * S + split)) * NPTS + pt_base;
#pragma unroll
    for (int k = 0; k < IPT; ++k)
        outp[k * TPB + t] = m[k];
}

// grid.x = RBLKS = 512. Fused reduce + final via last-block-done pattern:
// per-block sums -> bsum[bid]; release fence; acq_rel atomic counter; the
// 512th block re-reduces bsum[0..511] and writes the scalar. No cooperative
// launch, no same-address atomic storm (one atomic per block).
__global__ __launch_bounds__(TPB)
void chamfer_reduce_final(const float* __restrict__ p1, const float* __restrict__ p2,
                          const float* __restrict__ partial,
                          float* __restrict__ bsum, int* __restrict__ counter,
                          float* __restrict__ out) {
    __shared__ float wsum[TPB / 64];
    __shared__ int lastflag;

    int t     = threadIdx.x;
    int gid   = blockIdx.x * TPB + t;
    int point = gid & (NPTS - 1);
    int rest  = gid >> 13;
    int b     = rest & (BATCH - 1);
    int dir   = rest >> 3;

    const float* base = partial + ((size_t)(dir * BATCH + b) * S) * NPTS + point;
    float m = base[0];
#pragma unroll
    for (int s = 1; s < S; ++s)
        m = fminf(m, base[(size_t)s * NPTS]);

    float2 v = ((const float2*)(dir ? p2 : p1))[(size_t)b * NPTS + point];
    float d = m + fmaf(v.x, v.x, v.y * v.y);

#pragma unroll
    for (int off = 32; off > 0; off >>= 1)
        d += __shfl_down(d, off, 64);

    int lane = t & 63;
    int w    = t >> 6;
    if (lane == 0) wsum[w] = d;
    __syncthreads();
    if (t == 0) {
        bsum[blockIdx.x] = wsum[0] + wsum[1] + wsum[2] + wsum[3];
        __threadfence();   // device-scope release of the bsum store
        int n = __hip_atomic_fetch_add(counter, 1, __ATOMIC_ACQ_REL,
                                       __HIP_MEMORY_SCOPE_AGENT);
        lastflag = (n == RBLKS - 1);
    }
    __syncthreads();

    if (lastflag) {
        // this block observed all RBLKS-1 releases via the acquiring atomic
        float s = bsum[t] + bsum[t + TPB];
#pragma unroll
        for (int off = 32; off > 0; off >>= 1)
            s += __shfl_down(s, off, 64);
        if (lane == 0) wsum[w] = s;
        __syncthreads();
        if (t == 0)
            *out = (wsum[0] + wsum[1] + wsum[2] + wsum[3]) * (1.0f / NPTS);
    }
}

extern "C" void kernel_launch(void* const* d_in, const int* in_sizes, int n_in,
                              void* d_out, int out_size, void* d_ws, size_t ws_size,
                              hipStream_t stream) {
    const float* p1 = (const float*)d_in[0];
    const float* p2 = (const float*)d_in[1];
    float* out      = (float*)d_out;
    float* partial  = (float*)d_ws;            // 8 MB
    float* bsum     = partial + PARTN;         // 2 KB (512 floats)
    int*   counter  = (int*)(bsum + RBLKS);    // 4 B

    chamfer_partial<<<2 * BATCH * TILES * S, TPB, 0, stream>>>(p1, p2, partial, counter);
    chamfer_reduce_final<<<RBLKS, TPB, 0, stream>>>(p1, p2, partial, bsum, counter, out);
}